// Round 3
// baseline (371.392 us; speedup 1.0000x reference)
//
#include <hip/hip_runtime.h>

#define NN 4096
#define BB 8
#define DTILES 16  // blocks along d: 256 threads x 1 col = 256 d per block

// Partial-product kernel, v3: 1 destination column per thread, s-loop
// unrolled x8 so 8 independent P loads are in flight. pred[b,s] reads are
// wave-uniform -> scalar pipe. grid = (DTILES, S), block = 256.
__global__ void __launch_bounds__(256, 8)
diff_partial_kernel(const float* __restrict__ pred,
                    const float* __restrict__ P,
                    float* __restrict__ partial,  // [S][BB][NN]
                    int C)                        // s-chunk length = NN/S
{
    const int d  = blockIdx.x * 256 + threadIdx.x;
    const int s0 = blockIdx.y * C;

    float acc[BB];
#pragma unroll
    for (int b = 0; b < BB; ++b) acc[b] = 1.0f;

    const float* Pp = P + (size_t)s0 * NN + d;

    for (int c = 0; c < C; c += 8) {
        float pv[8];
#pragma unroll
        for (int k = 0; k < 8; ++k)
            pv[k] = Pp[(size_t)k * NN];

#pragma unroll
        for (int k = 0; k < 8; ++k) {
#pragma unroll
            for (int b = 0; b < BB; ++b) {
                acc[b] *= fmaf(-pred[b * NN + s0 + c + k], pv[k], 1.0f);
            }
        }
        Pp += (size_t)8 * NN;
    }

    float* out = partial + ((size_t)blockIdx.y * BB) * NN + d;
#pragma unroll
    for (int b = 0; b < BB; ++b)
        out[(size_t)b * NN] = acc[b];
}

// Combine kernel: pred_out[b,d] = 1 - prod over chunks of partial[chunk][b][d]
__global__ void __launch_bounds__(256)
diff_combine_kernel(const float* __restrict__ partial, int S,
                    float* __restrict__ pred_out)
{
    const int idx4 = (blockIdx.x * 256 + threadIdx.x) * 4;  // over BB*NN
    float4 acc = make_float4(1.0f, 1.0f, 1.0f, 1.0f);
    for (int ch = 0; ch < S; ++ch) {
        const float4 p = *(const float4*)(partial + (size_t)ch * BB * NN + idx4);
        acc.x *= p.x; acc.y *= p.y; acc.z *= p.z; acc.w *= p.w;
    }
    float4 r;
    r.x = 1.0f - acc.x; r.y = 1.0f - acc.y;
    r.z = 1.0f - acc.z; r.w = 1.0f - acc.w;
    *(float4*)(pred_out + idx4) = r;
}

extern "C" void kernel_launch(void* const* d_in, const int* in_sizes, int n_in,
                              void* d_out, int out_size, void* d_ws, size_t ws_size,
                              hipStream_t stream) {
    const float* preds = (const float*)d_in[0];
    // d_in[1] = seed_idx (unused, matches reference)
    const float* P     = (const float*)d_in[2];
    float* out = (float*)d_out;

    // ws layout: [pred ping buffer: BB*NN floats][partials: S*BB*NN floats]
    float* pred_ping = (float*)d_ws;
    float* partial   = pred_ping + (size_t)BB * NN;

    // largest S (<=256, power of 2) whose buffers fit in ws
    int S = 256;
    while (S > 1 && (size_t)(S + 1) * BB * NN * sizeof(float) > ws_size) S >>= 1;
    const int C = NN / S;  // >= 16

    dim3 pgrid(DTILES, S);
    dim3 cgrid((BB * NN) / (256 * 4));

    const float* cur = preds;
    for (int it = 0; it < 4; ++it) {
        float* dst = (it & 1) ? out : pred_ping;  // it: 0->ping,1->out,2->ping,3->out
        diff_partial_kernel<<<pgrid, 256, 0, stream>>>(cur, P, partial, C);
        diff_combine_kernel<<<cgrid, 256, 0, stream>>>(partial, S, dst);
        cur = dst;
    }
}

// Round 4
// 114.746 us; speedup vs baseline: 3.2367x; 3.2367x over previous
//
#include <hip/hip_runtime.h>

#define NN 4096
#define BB 8

__device__ __forceinline__ float loadP(const float* p) { return *p; }
__device__ __forceinline__ float loadP(const unsigned short* p) {
    unsigned int u = ((unsigned int)*p) << 16;   // bf16 -> f32
    return __uint_as_float(u);
}
__device__ __forceinline__ unsigned short to_bf16(float f) {
    unsigned int u = __float_as_uint(f);
    u += 0x7FFFu + ((u >> 16) & 1u);             // round to nearest even
    return (unsigned short)(u >> 16);
}

// One diffusion iteration: out[b,d] = 1 - prod_s (1 - pred[b,s] * P[s,d])
// grid = NN/16 = 256 blocks, block = 512 threads = 16 cols x 32 s-slices.
// Thread (slice,col) accumulates product over s in [slice*128, slice*128+128)
// for all 8 batches; wave shfl-reduce (4 slices/wave) + LDS across 8 waves.
// WRITE_BF: iteration 1 also emits a bf16 copy of P (each block owns its
// 16 columns exactly once) for iterations 2-4 to stream at half the bytes.
template <typename PT, bool WRITE_BF>
__global__ void __launch_bounds__(512)
diff_iter_kernel(const float* __restrict__ pred,
                 const PT* __restrict__ P,
                 unsigned short* __restrict__ Pbf,
                 float* __restrict__ out)
{
    const int col   = threadIdx.x & 15;
    const int slice = threadIdx.x >> 4;          // 0..31
    const int d     = blockIdx.x * 16 + col;
    const int s0    = slice * 128;

    float acc[BB];
#pragma unroll
    for (int b = 0; b < BB; ++b) acc[b] = 1.0f;

    const PT* Pp = P + (size_t)s0 * NN + d;

    for (int j = 0; j < 128; j += 8) {
        float pv[8];
#pragma unroll
        for (int k = 0; k < 8; ++k)
            pv[k] = loadP(Pp + (size_t)k * NN);

        if (WRITE_BF) {
#pragma unroll
            for (int k = 0; k < 8; ++k)
                Pbf[(size_t)(s0 + j + k) * NN + d] = to_bf16(pv[k]);
        }

#pragma unroll
        for (int k = 0; k < 8; ++k) {
            const int s = s0 + j + k;
#pragma unroll
            for (int b = 0; b < BB; ++b)
                acc[b] *= fmaf(-pred[b * NN + s], pv[k], 1.0f);
        }
        Pp += (size_t)8 * NN;
    }

    // product across the 4 slices resident in each wave (lane strides 16, 32)
#pragma unroll
    for (int b = 0; b < BB; ++b) {
        acc[b] *= __shfl_xor(acc[b], 16);
        acc[b] *= __shfl_xor(acc[b], 32);
    }

    __shared__ float red[8][16][9];              // [wave][col][batch], padded
    const int wid  = threadIdx.x >> 6;
    const int lane = threadIdx.x & 63;
    if (lane < 16) {                             // lane == col here
#pragma unroll
        for (int b = 0; b < BB; ++b) red[wid][lane][b] = acc[b];
    }
    __syncthreads();

    if (threadIdx.x < 128) {
        const int b  = threadIdx.x >> 4;
        const int c2 = threadIdx.x & 15;
        float pr = red[0][c2][b];
#pragma unroll
        for (int w = 1; w < 8; ++w) pr *= red[w][c2][b];
        out[b * NN + blockIdx.x * 16 + c2] = 1.0f - pr;
    }
}

extern "C" void kernel_launch(void* const* d_in, const int* in_sizes, int n_in,
                              void* d_out, int out_size, void* d_ws, size_t ws_size,
                              hipStream_t stream) {
    const float* preds = (const float*)d_in[0];
    // d_in[1] = seed_idx (unused, matches reference)
    const float* P     = (const float*)d_in[2];
    float* out  = (float*)d_out;
    float* ping = (float*)d_ws;                                  // [BB][NN] f32
    unsigned short* Pbf =
        (unsigned short*)((char*)d_ws + (size_t)BB * NN * sizeof(float));

    const bool use_bf =
        ws_size >= (size_t)BB * NN * sizeof(float) + (size_t)NN * NN * 2;

    dim3 grid(NN / 16);   // 256 blocks
    dim3 block(512);

    if (use_bf) {
        // it1: fp32 P -> compute + emit bf16 P;  it2-4: stream bf16 P
        diff_iter_kernel<float, true><<<grid, block, 0, stream>>>(preds, P, Pbf, ping);
        diff_iter_kernel<unsigned short, false><<<grid, block, 0, stream>>>(ping, Pbf, nullptr, out);
        diff_iter_kernel<unsigned short, false><<<grid, block, 0, stream>>>(out,  Pbf, nullptr, ping);
        diff_iter_kernel<unsigned short, false><<<grid, block, 0, stream>>>(ping, Pbf, nullptr, out);
    } else {
        diff_iter_kernel<float, false><<<grid, block, 0, stream>>>(preds, P, nullptr, ping);
        diff_iter_kernel<float, false><<<grid, block, 0, stream>>>(ping,  P, nullptr, out);
        diff_iter_kernel<float, false><<<grid, block, 0, stream>>>(out,   P, nullptr, ping);
        diff_iter_kernel<float, false><<<grid, block, 0, stream>>>(ping,  P, nullptr, out);
    }
}

// Round 5
// 103.424 us; speedup vs baseline: 3.5910x; 1.1095x over previous
//
#include <hip/hip_runtime.h>

#define NN 4096
#define BB 8

// ---------------------------------------------------------------------------
// transpose: predT[s][b] = preds[b][s]   (32K elements, trivial)
__global__ void __launch_bounds__(256)
transpose_pred(const float* __restrict__ preds, float* __restrict__ predT)
{
    const int g = blockIdx.x * 256 + threadIdx.x;      // over BB*NN
    const int b = g >> 12;
    const int s = g & (NN - 1);
    predT[s * BB + b] = preds[g];
}

// ---------------------------------------------------------------------------
// partial-product kernel. grid = (NN/256, SC), block = 256.
// Thread owns column d, s-chunk [ch*CHUNK, ch*CHUNK+CHUNK).
// pred read via predT[s][b]: wave-uniform contiguous -> scalar pipe.
// P read fully lane-coalesced (256 consecutive d per block).
// partial layout [b][ch][d] so the combine's reads are lane-coalesced.
template <int SC>
__global__ void __launch_bounds__(256, 8)
diff_partial(const float* __restrict__ predT,
             const float* __restrict__ P,
             float* __restrict__ partial)              // [BB][SC][NN]
{
    constexpr int CHUNK = NN / SC;
    const int d  = blockIdx.x * 256 + threadIdx.x;
    const int ch = blockIdx.y;
    const int s0 = ch * CHUNK;

    float acc[BB];
#pragma unroll
    for (int b = 0; b < BB; ++b) acc[b] = 1.0f;

    const float* Pp = P + (size_t)s0 * NN + d;
    const float* pt = predT + s0 * BB;

    for (int k = 0; k < CHUNK; k += 8) {
        float pv[8];
#pragma unroll
        for (int j = 0; j < 8; ++j)
            pv[j] = Pp[(size_t)j * NN];

#pragma unroll
        for (int j = 0; j < 8; ++j) {
#pragma unroll
            for (int b = 0; b < BB; ++b)
                acc[b] *= fmaf(-pt[(k + j) * BB + b], pv[j], 1.0f);
        }
        Pp += (size_t)8 * NN;
    }

#pragma unroll
    for (int b = 0; b < BB; ++b)
        partial[((size_t)b * SC + ch) * NN + d] = acc[b];
}

// ---------------------------------------------------------------------------
// combine: pred_new[b][d] = 1 - prod_ch partial[b][ch][d]
// 1 thread per output, loads lane-coalesced per ch, ch-loop unrolled x8.
// Writes predT layout for the next iteration; optionally also [b][d] to out.
template <int SC>
__global__ void __launch_bounds__(256)
diff_combine(const float* __restrict__ partial,
             float* __restrict__ predT_next,
             float* __restrict__ out, int write_out)
{
    const int g = blockIdx.x * 256 + threadIdx.x;      // 0 .. BB*NN-1
    const int b = g >> 12;
    const int d = g & (NN - 1);

    const float* pp = partial + (size_t)b * SC * NN + d;
    float prod = 1.0f;
#pragma unroll 8
    for (int ch = 0; ch < SC; ++ch)
        prod *= pp[(size_t)ch * NN];

    const float r = 1.0f - prod;
    predT_next[d * BB + b] = r;
    if (write_out) out[b * NN + d] = r;
}

// ---------------------------------------------------------------------------
template <int SC>
static void run_all(const float* preds, const float* P, float* out,
                    float* predT0, float* predT1, float* partial,
                    hipStream_t stream)
{
    dim3 pgrid(NN / 256, SC);
    dim3 cgrid((BB * NN) / 256);

    transpose_pred<<<cgrid, 256, 0, stream>>>(preds, predT0);

    float* pt_in  = predT0;
    float* pt_out = predT1;
    for (int it = 0; it < 4; ++it) {
        diff_partial<SC><<<pgrid, 256, 0, stream>>>(pt_in, P, partial);
        diff_combine<SC><<<cgrid, 256, 0, stream>>>(partial, pt_out, out,
                                                    it == 3 ? 1 : 0);
        float* t = pt_in; pt_in = pt_out; pt_out = t;
    }
}

extern "C" void kernel_launch(void* const* d_in, const int* in_sizes, int n_in,
                              void* d_out, int out_size, void* d_ws, size_t ws_size,
                              hipStream_t stream) {
    const float* preds = (const float*)d_in[0];
    // d_in[1] = seed_idx (unused, matches reference)
    const float* P     = (const float*)d_in[2];
    float* out = (float*)d_out;

    // ws layout: predT0 (128 KB) | predT1 (128 KB) | partial (SC*BB*NN*4)
    float* predT0  = (float*)d_ws;
    float* predT1  = predT0 + (size_t)NN * BB;
    float* partial = predT1 + (size_t)NN * BB;

    const size_t fixed = (size_t)2 * NN * BB * sizeof(float);
    if (ws_size >= fixed + (size_t)128 * BB * NN * sizeof(float)) {
        run_all<128>(preds, P, out, predT0, predT1, partial, stream);
    } else {
        run_all<32>(preds, P, out, predT0, predT1, partial, stream);
    }
}

// Round 6
// 75.246 us; speedup vs baseline: 4.9357x; 1.3745x over previous
//
#include <hip/hip_runtime.h>

#define NN 4096
#define BB 8
#define SC 32            // s-chunks (partial buffer depth)
#define WAVES 8          // 512-thread block
#define RPW 16           // rows per wave; chunk = WAVES*RPW = 128 rows

// ---------------------------------------------------------------------------
// transpose: predT[s][b] = preds[b][s]
__global__ void __launch_bounds__(256)
transpose_pred(const float* __restrict__ preds, float* __restrict__ predT)
{
    const int g = blockIdx.x * 256 + threadIdx.x;      // over BB*NN
    const int b = g >> 12;
    const int s = g & (NN - 1);
    predT[s * BB + b] = preds[g];
}

// ---------------------------------------------------------------------------
// partial kernel. grid = (NN/256 = 16 d-tiles, SC = 32), block = 512.
// Wave w handles rows [ch*128 + w*16, +16), lanes cover 256 d-cols as float4.
// P loads: global_load_dwordx4, 1KB/wave/instr. pred via scalar pipe
// (readfirstlane-forced uniform base -> s_load).
// Cross-wave product reduced in LDS; partial buffer is only [BB][SC][NN] = 4MB.
__global__ void __launch_bounds__(512, 4)
diff_partial(const float* __restrict__ predT,
             const float* __restrict__ P,
             float* __restrict__ partial)
{
    const int lane = threadIdx.x & 63;
    const int w    = __builtin_amdgcn_readfirstlane(threadIdx.x >> 6);
    const int d0   = blockIdx.x * 256 + lane * 4;
    const int ch   = blockIdx.y;
    const int row0 = ch * (WAVES * RPW) + w * RPW;

    float4 acc[BB];
#pragma unroll
    for (int b = 0; b < BB; ++b)
        acc[b] = make_float4(1.0f, 1.0f, 1.0f, 1.0f);

    const float* Pp = P + (size_t)row0 * NN + d0;
    const float* pt = predT + row0 * BB;

#pragma unroll
    for (int k = 0; k < RPW; k += 4) {
        float4 pv[4];
#pragma unroll
        for (int j = 0; j < 4; ++j)
            pv[j] = *(const float4*)(Pp + (size_t)(k + j) * NN);

#pragma unroll
        for (int j = 0; j < 4; ++j) {
#pragma unroll
            for (int b = 0; b < BB; ++b) {
                const float p = pt[(k + j) * BB + b];   // scalar (uniform)
                acc[b].x *= fmaf(-p, pv[j].x, 1.0f);
                acc[b].y *= fmaf(-p, pv[j].y, 1.0f);
                acc[b].z *= fmaf(-p, pv[j].z, 1.0f);
                acc[b].w *= fmaf(-p, pv[j].w, 1.0f);
            }
        }
    }

    __shared__ float4 red[WAVES][BB][64];               // 64 KB
#pragma unroll
    for (int b = 0; b < BB; ++b)
        red[w][b][lane] = acc[b];
    __syncthreads();

    // 512 threads: thread t reduces (b = t>>6, col4 = t&63) across 8 waves
    const int b  = threadIdx.x >> 6;
    const int c4 = threadIdx.x & 63;
    float4 pr = red[0][b][c4];
#pragma unroll
    for (int w2 = 1; w2 < WAVES; ++w2) {
        const float4 v = red[w2][b][c4];
        pr.x *= v.x; pr.y *= v.y; pr.z *= v.z; pr.w *= v.w;
    }
    *(float4*)(partial + ((size_t)b * SC + ch) * NN + blockIdx.x * 256 + c4 * 4) = pr;
}

// ---------------------------------------------------------------------------
// combine: pred_new[b][d] = 1 - prod_ch partial[b][ch][d]; 32-deep unrolled.
__global__ void __launch_bounds__(256)
diff_combine(const float* __restrict__ partial,
             float* __restrict__ predT_next,
             float* __restrict__ out, int write_out)
{
    const int g = blockIdx.x * 256 + threadIdx.x;       // over BB*NN
    const int b = g >> 12;
    const int d = g & (NN - 1);

    const float* pp = partial + (size_t)b * SC * NN + d;
    float prod = 1.0f;
#pragma unroll
    for (int ch = 0; ch < SC; ++ch)
        prod *= pp[(size_t)ch * NN];

    const float r = 1.0f - prod;
    predT_next[d * BB + b] = r;
    if (write_out) out[g] = r;
}

// ---------------------------------------------------------------------------
extern "C" void kernel_launch(void* const* d_in, const int* in_sizes, int n_in,
                              void* d_out, int out_size, void* d_ws, size_t ws_size,
                              hipStream_t stream) {
    const float* preds = (const float*)d_in[0];
    // d_in[1] = seed_idx (unused, matches reference)
    const float* P     = (const float*)d_in[2];
    float* out = (float*)d_out;

    float* predT0  = (float*)d_ws;                       // [NN][BB]
    float* predT1  = predT0 + (size_t)NN * BB;
    float* partial = predT1 + (size_t)NN * BB;           // [BB][SC][NN] = 4 MB

    dim3 pgrid(NN / 256, SC);
    dim3 cgrid((BB * NN) / 256);

    transpose_pred<<<cgrid, 256, 0, stream>>>(preds, predT0);

    float* pt_in  = predT0;
    float* pt_out = predT1;
    for (int it = 0; it < 4; ++it) {
        diff_partial<<<pgrid, 512, 0, stream>>>(pt_in, P, partial);
        diff_combine<<<cgrid, 256, 0, stream>>>(partial, pt_out, out,
                                                it == 3 ? 1 : 0);
        float* t = pt_in; pt_in = pt_out; pt_out = t;
    }
}